// Round 7
// baseline (358.176 us; speedup 1.0000x reference)
//
#include <hip/hip_runtime.h>
#include <hip/hip_bf16.h>

#define NN 50000
#define NE 800000
#define KD 768
#define HIDD 128
#define NC 6

typedef __attribute__((ext_vector_type(8))) short bf16x8;
typedef __attribute__((ext_vector_type(4))) float f32x4;

__device__ __forceinline__ ushort f2bf(float f) {
    union { float f; unsigned u; } v; v.f = f;
    unsigned u = v.u + 0x7FFF + ((v.u >> 16) & 1);   // round-to-nearest-even
    return (ushort)(u >> 16);
}
__device__ __forceinline__ float bf2f(ushort h) {
    union { unsigned u; float f; } v; v.u = ((unsigned)h) << 16;
    return v.f;
}
__device__ __forceinline__ void gll16(const void* g, void* l) {
    __builtin_amdgcn_global_load_lds((const __attribute__((address_space(1))) void*)g,
                                     (__attribute__((address_space(3))) void*)l, 16, 0, 0);
}

// ---------------- weight prep granule (packed, gll-ready, swizzle baked in) ----------------

template <int KTOT>
__device__ __forceinline__ void pack_granule(const float* __restrict__ W,
                                             ushort* __restrict__ WTp, int gi) {
    const int KS = KTOT / 64;
    int ci = gi / (KS * 64);
    int rem = gi % (KS * 64);
    int ks = rem >> 6;
    int lane = rem & 63;
    int lr = lane >> 3;
    int lg = (lane & 7) ^ lr;
    int c = ci * 8 + lr;
    ushort tmp[8];
#pragma unroll
    for (int j = 0; j < 8; ++j)
        tmp[j] = f2bf(W[(size_t)(ks * 64 + lg * 8 + j) * HIDD + c]);
    *(bf16x8*)&WTp[(size_t)gi * 8] = *(bf16x8*)tmp;
}

// ---------------- fused: edge count (atomics) + weight pack ----------------

__global__ void count_prep_kernel(const int* __restrict__ ei, int* __restrict__ cnt,
                                  const float* __restrict__ W1, const float* __restrict__ W2,
                                  ushort* __restrict__ WT1p, ushort* __restrict__ WT2p) {
    const int CB = NE / 256;                // 3125
    const int G1 = 16 * (KD / 64) * 64;     // 12288
    const int G2 = 16 * (HIDD / 64) * 64;   // 2048
    int b = blockIdx.x;
    if (b < CB) {
        int e = b * 256 + threadIdx.x;
        int d = ei[NE + e];
        d = min(max(d, 0), NN - 1);
        atomicAdd(&cnt[d], 1);
    } else {
        int gi = (b - CB) * 256 + threadIdx.x;
        if (gi < G1) pack_granule<KD>(W1, WT1p, gi);
        else if (gi < G1 + G2) pack_granule<HIDD>(W2, WT2p, gi - G1);
    }
}

// ---------------- CSR scan ----------------

__global__ void scan_blocks_kernel(const int* __restrict__ cnt, int* __restrict__ row_ptr,
                                   float* __restrict__ dinv, int* __restrict__ bsum) {
    __shared__ int s[256];
    int t = threadIdx.x;
    int base = blockIdx.x * 1024 + t * 4;
    int v[4];
    int sum = 0;
#pragma unroll
    for (int j = 0; j < 4; ++j) {
        int i = base + j;
        v[j] = (i < NN) ? cnt[i] : 0;
        sum += v[j];
    }
    s[t] = sum;
    __syncthreads();
    for (int off = 1; off < 256; off <<= 1) {
        int val = (t >= off) ? s[t - off] : 0;
        __syncthreads();
        s[t] += val;
        __syncthreads();
    }
    int excl = s[t] - sum;
    if (t == 0) bsum[blockIdx.x] = s[255];
    int run = excl;
#pragma unroll
    for (int j = 0; j < 4; ++j) {
        int i = base + j;
        if (i < NN) {
            row_ptr[i] = run;
            dinv[i] = rsqrtf((float)(v[j] + 1));
            run += v[j];
        }
    }
}

__global__ void scan_add_kernel(int* __restrict__ row_ptr, int* __restrict__ cursor,
                                const int* __restrict__ bsum) {
    int i = blockIdx.x * blockDim.x + threadIdx.x;
    if (i >= NN) return;
    int chunk = i >> 10;
    int off = 0;
    for (int k = 0; k < chunk; ++k) off += bsum[k];
    int r = row_ptr[i] + off;
    row_ptr[i] = r;
    cursor[i] = r;
    if (i == 0) {
        int tot = 0;
        for (int k = 0; k < 49; ++k) tot += bsum[k];
        row_ptr[NN] = tot;
    }
}

__global__ void fill_kernel(const int* __restrict__ ei, int* __restrict__ cursor,
                            int* __restrict__ col) {
    int e = blockIdx.x * blockDim.x + threadIdx.x;
    if (e >= NE) return;
    int sidx = ei[e];
    int d = ei[NE + e];
    sidx = min(max(sidx, 0), NN - 1);
    d = min(max(d, 0), NN - 1);
    int pos = atomicAdd(&cursor[d], 1);
    col[pos] = sidx;
}

// ---------------- MFMA GEMM1: slab-major out[slab][r][32] = bf16(dinv[r]*(x@W1)) ----------------
// BM=64, BN=128, BK=64. 782 blocks, 4 waves (2x2), wave tile 32x64.

__global__ __launch_bounds__(256) void mfma_gemm1(const float* __restrict__ A,
                                                  const ushort* __restrict__ WTp,
                                                  const float* __restrict__ dinv,
                                                  ushort* __restrict__ out, int M) {
    const int KS = KD / 64;
    __shared__ ushort As[64 * 64];
    __shared__ ushort Bs[128 * 64];
    int t = threadIdx.x;
    int lane = t & 63;
    int wid = t >> 6;
    int wr = wid >> 1, wc = wid & 1;
    int row0 = blockIdx.x * 64;
    f32x4 acc[2][4] = {};

    for (int ks = 0; ks < KS; ++ks) {
        int k0 = ks * 64;
#pragma unroll
        for (int it = 0; it < 4; ++it) {
            int r = (t >> 4) + it * 16;
            int k4 = t & 15;
            int gr = min(row0 + r, M - 1);
            float4 v = *(const float4*)&A[(size_t)gr * KD + k0 + k4 * 4];
            ushort4 w;
            w.x = f2bf(v.x); w.y = f2bf(v.y); w.z = f2bf(v.z); w.w = f2bf(v.w);
            int g = k4 >> 1, half = k4 & 1;
            *(ushort4*)&As[r * 64 + ((g ^ (r & 7)) * 8) + half * 4] = w;
        }
#pragma unroll
        for (int it = 0; it < 4; ++it) {
            int ci = wid * 4 + it;
            gll16(&WTp[(size_t)((ci * KS + ks) * 64 + lane) * 8], &Bs[ci * 512]);
        }
        __syncthreads();
#pragma unroll
        for (int h = 0; h < 2; ++h) {
            int q = h * 4 + (lane >> 4);
            bf16x8 a[2];
#pragma unroll
            for (int m = 0; m < 2; ++m) {
                int r = wr * 32 + m * 16 + (lane & 15);
                a[m] = *(const bf16x8*)&As[r * 64 + (q ^ (r & 7)) * 8];
            }
#pragma unroll
            for (int n = 0; n < 4; ++n) {
                int c = wc * 64 + n * 16 + (lane & 15);
                bf16x8 b = *(const bf16x8*)&Bs[c * 64 + (q ^ (c & 7)) * 8];
#pragma unroll
                for (int m = 0; m < 2; ++m)
                    acc[m][n] = __builtin_amdgcn_mfma_f32_16x16x32_bf16(a[m], b, acc[m][n], 0, 0, 0);
            }
        }
        __syncthreads();
    }
#pragma unroll
    for (int m = 0; m < 2; ++m) {
#pragma unroll
        for (int reg = 0; reg < 4; ++reg) {
            int row = row0 + wr * 32 + m * 16 + (lane >> 4) * 4 + reg;
            if (row < M) {
                float d = dinv[row];
#pragma unroll
                for (int n = 0; n < 4; ++n) {
                    int colg = wc * 64 + n * 16 + (lane & 15);
                    ushort* dst = out + (size_t)(colg >> 5) * NN * 32;
                    dst[(size_t)row * 32 + (colg & 31)] = f2bf(acc[m][n][reg] * d);
                }
            }
        }
    }
}

// ---------------- MFMA GEMM2: A read from h1 slabs, out to hs2 slabs ----------------

__global__ __launch_bounds__(256) void mfma_gemm2(const ushort* __restrict__ A,
                                                  const ushort* __restrict__ WTp,
                                                  const float* __restrict__ dinv,
                                                  ushort* __restrict__ out, int M) {
    const int KS = HIDD / 64;   // 2
    __shared__ ushort As[64 * 64];
    __shared__ ushort Bs[128 * 64];
    int t = threadIdx.x;
    int lane = t & 63;
    int wid = t >> 6;
    int wr = wid >> 1, wc = wid & 1;
    int row0 = blockIdx.x * 64;
    f32x4 acc[2][4] = {};

    int lr = lane >> 3;
    int lg = (lane & 7) ^ lr;

    for (int ks = 0; ks < KS; ++ks) {
        int k0 = ks * 64;
#pragma unroll
        for (int it = 0; it < 2; ++it) {
            int ci2 = wid * 2 + it;
            int r = ci2 * 8 + lr;
            int gr = min(row0 + r, M - 1);
            int kk = k0 + lg * 8;
            const ushort* src = A + (size_t)(kk >> 5) * NN * 32 + (size_t)gr * 32 + (kk & 31);
            gll16(src, &As[ci2 * 512]);
        }
#pragma unroll
        for (int it = 0; it < 4; ++it) {
            int ci = wid * 4 + it;
            gll16(&WTp[(size_t)((ci * KS + ks) * 64 + lane) * 8], &Bs[ci * 512]);
        }
        __syncthreads();
#pragma unroll
        for (int h = 0; h < 2; ++h) {
            int q = h * 4 + (lane >> 4);
            bf16x8 a[2];
#pragma unroll
            for (int m = 0; m < 2; ++m) {
                int r = wr * 32 + m * 16 + (lane & 15);
                a[m] = *(const bf16x8*)&As[r * 64 + (q ^ (r & 7)) * 8];
            }
#pragma unroll
            for (int n = 0; n < 4; ++n) {
                int c = wc * 64 + n * 16 + (lane & 15);
                bf16x8 b = *(const bf16x8*)&Bs[c * 64 + (q ^ (c & 7)) * 8];
#pragma unroll
                for (int m = 0; m < 2; ++m)
                    acc[m][n] = __builtin_amdgcn_mfma_f32_16x16x32_bf16(a[m], b, acc[m][n], 0, 0, 0);
            }
        }
        __syncthreads();
    }
#pragma unroll
    for (int m = 0; m < 2; ++m) {
#pragma unroll
        for (int reg = 0; reg < 4; ++reg) {
            int row = row0 + wr * 32 + m * 16 + (lane >> 4) * 4 + reg;
            if (row < M) {
                float d = dinv[row];
#pragma unroll
                for (int n = 0; n < 4; ++n) {
                    int colg = wc * 64 + n * 16 + (lane & 15);
                    ushort* dst = out + (size_t)(colg >> 5) * NN * 32;
                    dst[(size_t)row * 32 + (colg & 31)] = f2bf(acc[m][n][reg] * d);
                }
            }
        }
    }
}

// ---------------- slab-pass CSR aggregation ----------------
// Grid = 4 passes x 12500 blocks (pass-major => ~one 3.2MB slab hot in L2 at a time).
// One wave per node; 16-lane quad per edge (64B slice); 4 edges in flight x 4-deep unroll.
// MODE 0: bf16 out = bf16(relu(dinv*sum + bias))     [h1 slabs]
// MODE 1: fp32 out = relu(dinv*sum + bias)           [h2 slabs for heads]

template <int MODE>
__global__ void agg_pass_kernel(const ushort* __restrict__ hs, const int* __restrict__ row_ptr,
                                const int* __restrict__ col, const float* __restrict__ dinv,
                                const float* __restrict__ bias, void* __restrict__ outp) {
    const int BPP = NN / 4;   // 12500
    int pass = blockIdx.x / BPP;
    int nb = blockIdx.x % BPP;
    int wv = threadIdx.x >> 6;
    int lane = threadIdx.x & 63;
    int q = lane >> 4, pos = lane & 15;
    int i = nb * 4 + wv;
    const ushort* slab = hs + (size_t)pass * NN * 32;

    float ax = 0.f, ay = 0.f;
    if (q == 0) {
        unsigned self = *(const unsigned*)&slab[(size_t)i * 32 + pos * 2];
        ax = bf2f((ushort)(self & 0xffff));
        ay = bf2f((ushort)(self >> 16));
    }
    int e0 = row_ptr[i], e1 = row_ptr[i + 1];
    int e = e0;
    for (; e + 16 <= e1; e += 16) {
        int j0 = col[e + q], j1 = col[e + 4 + q], j2 = col[e + 8 + q], j3 = col[e + 12 + q];
        unsigned w0 = *(const unsigned*)&slab[(size_t)j0 * 32 + pos * 2];
        unsigned w1 = *(const unsigned*)&slab[(size_t)j1 * 32 + pos * 2];
        unsigned w2 = *(const unsigned*)&slab[(size_t)j2 * 32 + pos * 2];
        unsigned w3 = *(const unsigned*)&slab[(size_t)j3 * 32 + pos * 2];
        ax += bf2f((ushort)(w0 & 0xffff)) + bf2f((ushort)(w1 & 0xffff)) +
              bf2f((ushort)(w2 & 0xffff)) + bf2f((ushort)(w3 & 0xffff));
        ay += bf2f((ushort)(w0 >> 16)) + bf2f((ushort)(w1 >> 16)) +
              bf2f((ushort)(w2 >> 16)) + bf2f((ushort)(w3 >> 16));
    }
    for (; e < e1; e += 4) {
        int idx = e + q;
        if (idx < e1) {
            int j = col[idx];
            unsigned w = *(const unsigned*)&slab[(size_t)j * 32 + pos * 2];
            ax += bf2f((ushort)(w & 0xffff));
            ay += bf2f((ushort)(w >> 16));
        }
    }
    // reduce quad partials (deterministic)
    ax += __shfl_xor(ax, 16); ax += __shfl_xor(ax, 32);
    ay += __shfl_xor(ay, 16); ay += __shfl_xor(ay, 32);

    if (q == 0) {
        float d = dinv[i];
        int c0 = pass * 32 + pos * 2;
        float ox = fmaxf(fmaf(ax, d, bias[c0]), 0.f);
        float oy = fmaxf(fmaf(ay, d, bias[c0 + 1]), 0.f);
        if (MODE == 0) {
            ushort* out = (ushort*)outp + (size_t)pass * NN * 32;
            unsigned o = (unsigned)f2bf(ox) | ((unsigned)f2bf(oy) << 16);
            *(unsigned*)&out[(size_t)i * 32 + pos * 2] = o;
        } else {
            float* out = (float*)outp + (size_t)pass * NN * 32;
            *(float2*)&out[(size_t)i * 32 + pos * 2] = make_float2(ox, oy);
        }
    }
}

// ---------------- heads: read fp32 h2 slabs, two 128x6 matvecs + log_softmax ----------------

__global__ void heads_kernel(const float* __restrict__ h2f,
                             const float* __restrict__ Wi, const float* __restrict__ bi,
                             const float* __restrict__ Wl, const float* __restrict__ bl,
                             float* __restrict__ out) {
    int wv = threadIdx.x >> 6;
    int l = threadIdx.x & 63;
    int i = blockIdx.x * 4 + wv;
    // lane l holds cols 2l, 2l+1: slab = l>>4, offset = (2l)&31
    float2 v = *(const float2*)&h2f[(size_t)(l >> 4) * NN * 32 + (size_t)i * 32 + ((2 * l) & 31)];
    float ox = v.x, oy = v.y;

    float4 u0 = *(const float4*)&Wi[l * 12];
    float4 u1 = *(const float4*)&Wi[l * 12 + 4];
    float4 u2 = *(const float4*)&Wi[l * 12 + 8];
    float pi[6];
    pi[0] = ox * u0.x + oy * u1.z;
    pi[1] = ox * u0.y + oy * u1.w;
    pi[2] = ox * u0.z + oy * u2.x;
    pi[3] = ox * u0.w + oy * u2.y;
    pi[4] = ox * u1.x + oy * u2.z;
    pi[5] = ox * u1.y + oy * u2.w;
    u0 = *(const float4*)&Wl[l * 12];
    u1 = *(const float4*)&Wl[l * 12 + 4];
    u2 = *(const float4*)&Wl[l * 12 + 8];
    float pl[6];
    pl[0] = ox * u0.x + oy * u1.z;
    pl[1] = ox * u0.y + oy * u1.w;
    pl[2] = ox * u0.z + oy * u2.x;
    pl[3] = ox * u0.w + oy * u2.y;
    pl[4] = ox * u1.x + oy * u2.z;
    pl[5] = ox * u1.y + oy * u2.w;
#pragma unroll
    for (int off = 1; off < 64; off <<= 1) {
#pragma unroll
        for (int c = 0; c < 6; ++c) {
            pi[c] += __shfl_xor(pi[c], off);
            pl[c] += __shfl_xor(pl[c], off);
        }
    }
#pragma unroll
    for (int c = 0; c < 6; ++c) {
        pi[c] += bi[c];
        pl[c] += bl[c];
    }
    float mi = fmaxf(fmaxf(fmaxf(pi[0], pi[1]), fmaxf(pi[2], pi[3])), fmaxf(pi[4], pi[5]));
    float ml = fmaxf(fmaxf(fmaxf(pl[0], pl[1]), fmaxf(pl[2], pl[3])), fmaxf(pl[4], pl[5]));
    float si = 0.f, sl = 0.f;
#pragma unroll
    for (int c = 0; c < 6; ++c) {
        si += expf(pi[c] - mi);
        sl += expf(pl[c] - ml);
    }
    float lsi = mi + logf(si), lsl = ml + logf(sl);
#pragma unroll
    for (int c = 0; c < 6; ++c) {
        if (l == c)     out[(size_t)i * NC + c] = pi[c] - lsi;
        if (l == 6 + c) out[(size_t)NN * NC + (size_t)i * NC + c] = pl[c] - lsl;
    }
}

extern "C" void kernel_launch(void* const* d_in, const int* in_sizes, int n_in,
                              void* d_out, int out_size, void* d_ws, size_t ws_size,
                              hipStream_t stream) {
    const float* x  = (const float*)d_in[0];
    const int*   ei = (const int*)d_in[1];
    const float* W1 = (const float*)d_in[2];
    const float* b1 = (const float*)d_in[3];
    const float* W2 = (const float*)d_in[4];
    const float* b2 = (const float*)d_in[5];
    const float* Wi = (const float*)d_in[6];
    const float* bi = (const float*)d_in[7];
    const float* Wl = (const float*)d_in[8];
    const float* bl = (const float*)d_in[9];
    float* out = (float*)d_out;

    uint8_t* p = (uint8_t*)d_ws;
    auto alloc = [&](size_t bytes) {
        void* r = (void*)p;
        p += (bytes + 255) / 256 * 256;
        return r;
    };
    int* row_ptr = (int*)alloc((NN + 1) * sizeof(int));
    int* cursor  = (int*)alloc(NN * sizeof(int));
    int* col     = (int*)alloc(NE * sizeof(int));
    int* bsum    = (int*)alloc(64 * sizeof(int));
    float* dinv  = (float*)alloc(NN * sizeof(float));
    ushort* WT1p = (ushort*)alloc((size_t)KD * HIDD * sizeof(ushort));
    ushort* WT2p = (ushort*)alloc((size_t)HIDD * HIDD * sizeof(ushort));
    ushort* bufA = (ushort*)alloc((size_t)NN * HIDD * sizeof(ushort));  // hs1 / hs2 slabs
    ushort* bufB = (ushort*)alloc((size_t)NN * HIDD * sizeof(ushort));  // h1 slabs
    float*  bufC = (float*)alloc((size_t)NN * HIDD * sizeof(float));    // h2 fp32 slabs

    const int CB = NE / 256;   // 3125
    const int PB = 56;         // pack blocks

    hipMemsetAsync(cursor, 0, NN * sizeof(int), stream);
    count_prep_kernel<<<CB + PB, 256, 0, stream>>>(ei, cursor, W1, W2, WT1p, WT2p);
    scan_blocks_kernel<<<49, 256, 0, stream>>>(cursor, row_ptr, dinv, bsum);
    scan_add_kernel<<<(NN + 255) / 256, 256, 0, stream>>>(row_ptr, cursor, bsum);
    fill_kernel<<<CB, 256, 0, stream>>>(ei, cursor, col);

    const int grid = (NN + 63) / 64;   // 782
    const int AGG_GRID = 4 * (NN / 4); // 4 passes x 12500
    // layer 1
    mfma_gemm1<<<grid, 256, 0, stream>>>(x, WT1p, dinv, bufA, NN);
    agg_pass_kernel<0><<<AGG_GRID, 256, 0, stream>>>(bufA, row_ptr, col, dinv, b1, bufB);
    // layer 2
    mfma_gemm2<<<grid, 256, 0, stream>>>(bufB, WT2p, dinv, bufA, NN);
    agg_pass_kernel<1><<<AGG_GRID, 256, 0, stream>>>(bufA, row_ptr, col, dinv, b2, bufC);
    // heads
    heads_kernel<<<NN / 4, 256, 0, stream>>>(bufC, Wi, bi, Wl, bl, out);
}

// Round 8
// 257.188 us; speedup vs baseline: 1.3927x; 1.3927x over previous
//
#include <hip/hip_runtime.h>
#include <hip/hip_bf16.h>

#define NN 50000
#define NE 800000
#define KD 768
#define HIDD 128
#define NC 6

typedef __attribute__((ext_vector_type(8))) short bf16x8;
typedef __attribute__((ext_vector_type(4))) float f32x4;

__device__ __forceinline__ ushort f2bf(float f) {
    union { float f; unsigned u; } v; v.f = f;
    unsigned u = v.u + 0x7FFF + ((v.u >> 16) & 1);   // round-to-nearest-even
    return (ushort)(u >> 16);
}
__device__ __forceinline__ float bf2f(ushort h) {
    union { unsigned u; float f; } v; v.u = ((unsigned)h) << 16;
    return v.f;
}
__device__ __forceinline__ void gll16(const void* g, void* l) {
    __builtin_amdgcn_global_load_lds((const __attribute__((address_space(1))) void*)g,
                                     (__attribute__((address_space(3))) void*)l, 16, 0, 0);
}

// ---------------- weight prep granule (packed, gll-ready, swizzle baked in) ----------------

template <int KTOT>
__device__ __forceinline__ void pack_granule(const float* __restrict__ W,
                                             ushort* __restrict__ WTp, int gi) {
    const int KS = KTOT / 64;
    int ci = gi / (KS * 64);
    int rem = gi % (KS * 64);
    int ks = rem >> 6;
    int lane = rem & 63;
    int lr = lane >> 3;
    int lg = (lane & 7) ^ lr;
    int c = ci * 8 + lr;
    ushort tmp[8];
#pragma unroll
    for (int j = 0; j < 8; ++j)
        tmp[j] = f2bf(W[(size_t)(ks * 64 + lg * 8 + j) * HIDD + c]);
    *(bf16x8*)&WTp[(size_t)gi * 8] = *(bf16x8*)tmp;
}

// ---------------- K1: fused edge count (atomics) + weight pack ----------------

__global__ void count_prep_kernel(const int* __restrict__ ei, int* __restrict__ cnt,
                                  const float* __restrict__ W1, const float* __restrict__ W2,
                                  ushort* __restrict__ WT1p, ushort* __restrict__ WT2p) {
    const int CB = NE / 256;                // 3125
    const int G1 = 16 * (KD / 64) * 64;     // 12288
    const int G2 = 16 * (HIDD / 64) * 64;   // 2048
    int b = blockIdx.x;
    if (b < CB) {
        int e = b * 256 + threadIdx.x;
        int d = ei[NE + e];
        d = min(max(d, 0), NN - 1);
        atomicAdd(&cnt[d], 1);
    } else {
        int gi = (b - CB) * 256 + threadIdx.x;
        if (gi < G1) pack_granule<KD>(W1, WT1p, gi);
        else if (gi < G1 + G2) pack_granule<HIDD>(W2, WT2p, gi - G1);
    }
}

// ---------------- K2: fused CSR scan (196 blocks, internal device barrier) ----------------
// Phase A (blocks 0..48): per-1024-chunk local scan -> row_ptr (local excl), dinv, bsum.
// Device barrier (all 196 blocks co-resident on 256 CUs -> deadlock-free).
// Phase B (all blocks): add block offsets, write cursor; i==0 writes row_ptr[NN].

__global__ __launch_bounds__(256) void scan_fused_kernel(
    const int* __restrict__ cnt, int* __restrict__ row_ptr, float* __restrict__ dinv,
    int* __restrict__ bsum, int* __restrict__ cursor, int* __restrict__ done) {
    int t = threadIdx.x;
    int b = blockIdx.x;
    if (b < 49) {
        __shared__ int s[256];
        int base = b * 1024 + t * 4;
        int v[4];
        int sum = 0;
#pragma unroll
        for (int j = 0; j < 4; ++j) {
            int i = base + j;
            v[j] = (i < NN) ? cnt[i] : 0;
            sum += v[j];
        }
        s[t] = sum;
        __syncthreads();
        for (int off = 1; off < 256; off <<= 1) {
            int val = (t >= off) ? s[t - off] : 0;
            __syncthreads();
            s[t] += val;
            __syncthreads();
        }
        int excl = s[t] - sum;
        if (t == 0) bsum[b] = s[255];
        int run = excl;
#pragma unroll
        for (int j = 0; j < 4; ++j) {
            int i = base + j;
            if (i < NN) {
                row_ptr[i] = run;
                dinv[i] = rsqrtf((float)(v[j] + 1));
                run += v[j];
            }
        }
        __threadfence();
        __syncthreads();
        if (t == 0) atomicAdd(done, 1);
    }
    // barrier: wait for all 49 phase-A blocks
    if (t == 0) {
        while (atomicAdd(done, 0) < 49) { __builtin_amdgcn_s_sleep(2); }
    }
    __syncthreads();
    __threadfence();
    // phase B
    int i = b * 256 + t;
    if (i < NN) {
        int chunk = i >> 10;
        int off = 0;
        for (int k = 0; k < chunk; ++k) off += bsum[k];
        int r = row_ptr[i] + off;
        row_ptr[i] = r;
        cursor[i] = r;
        if (i == 0) {
            int tot = 0;
            for (int k = 0; k < 49; ++k) tot += bsum[k];
            row_ptr[NN] = tot;
        }
    }
}

// ---------------- K3: fused CSR fill + MFMA GEMM1 (independent, block-range split) ----------------
// blocks [0,3125): fill col via cursor atomics.
// blocks [3125,3907): gemm1 BM=64,BN=128,BK=64; hs1 = bf16(dinv*(x@W1)).

__global__ __launch_bounds__(256) void fill_gemm1_kernel(
    const int* __restrict__ ei, int* __restrict__ cursor, int* __restrict__ col,
    const float* __restrict__ A, const ushort* __restrict__ WTp,
    const float* __restrict__ dinv, ushort* __restrict__ out, int M) {
    const int FB = NE / 256;   // 3125
    __shared__ ushort As[64 * 64];
    __shared__ ushort Bs[128 * 64];
    if (blockIdx.x < FB) {
        int e = blockIdx.x * 256 + threadIdx.x;
        int sidx = ei[e];
        int d = ei[NE + e];
        sidx = min(max(sidx, 0), NN - 1);
        d = min(max(d, 0), NN - 1);
        int pos = atomicAdd(&cursor[d], 1);
        col[pos] = sidx;
        return;
    }
    const int KS = KD / 64;
    int t = threadIdx.x;
    int lane = t & 63;
    int wid = t >> 6;
    int wr = wid >> 1, wc = wid & 1;
    int row0 = (blockIdx.x - FB) * 64;
    f32x4 acc[2][4] = {};

    for (int ks = 0; ks < KS; ++ks) {
        int k0 = ks * 64;
#pragma unroll
        for (int it = 0; it < 4; ++it) {
            int r = (t >> 4) + it * 16;
            int k4 = t & 15;
            int gr = min(row0 + r, M - 1);
            float4 v = *(const float4*)&A[(size_t)gr * KD + k0 + k4 * 4];
            ushort4 w;
            w.x = f2bf(v.x); w.y = f2bf(v.y); w.z = f2bf(v.z); w.w = f2bf(v.w);
            int g = k4 >> 1, half = k4 & 1;
            *(ushort4*)&As[r * 64 + ((g ^ (r & 7)) * 8) + half * 4] = w;
        }
#pragma unroll
        for (int it = 0; it < 4; ++it) {
            int ci = wid * 4 + it;
            gll16(&WTp[(size_t)((ci * KS + ks) * 64 + lane) * 8], &Bs[ci * 512]);
        }
        __syncthreads();
#pragma unroll
        for (int h = 0; h < 2; ++h) {
            int q = h * 4 + (lane >> 4);
            bf16x8 a[2];
#pragma unroll
            for (int m = 0; m < 2; ++m) {
                int r = wr * 32 + m * 16 + (lane & 15);
                a[m] = *(const bf16x8*)&As[r * 64 + (q ^ (r & 7)) * 8];
            }
#pragma unroll
            for (int n = 0; n < 4; ++n) {
                int c = wc * 64 + n * 16 + (lane & 15);
                bf16x8 b = *(const bf16x8*)&Bs[c * 64 + (q ^ (c & 7)) * 8];
#pragma unroll
                for (int m = 0; m < 2; ++m)
                    acc[m][n] = __builtin_amdgcn_mfma_f32_16x16x32_bf16(a[m], b, acc[m][n], 0, 0, 0);
            }
        }
        __syncthreads();
    }
#pragma unroll
    for (int m = 0; m < 2; ++m) {
#pragma unroll
        for (int reg = 0; reg < 4; ++reg) {
            int row = row0 + wr * 32 + m * 16 + (lane >> 4) * 4 + reg;
            if (row < M) {
                float d = dinv[row];
#pragma unroll
                for (int n = 0; n < 4; ++n) {
                    int colg = wc * 64 + n * 16 + (lane & 15);
                    out[(size_t)row * 128 + colg] = f2bf(acc[m][n][reg] * d);
                }
            }
        }
    }
}

// ---------------- MFMA GEMM2: hs2 = bf16(dinv*(h1@W2)), bf16 A via gll ----------------

__global__ __launch_bounds__(256) void mfma_gemm2(const ushort* __restrict__ A,
                                                  const ushort* __restrict__ WTp,
                                                  const float* __restrict__ dinv,
                                                  ushort* __restrict__ out, int M) {
    const int KS = HIDD / 64;   // 2
    __shared__ ushort As[64 * 64];
    __shared__ ushort Bs[128 * 64];
    int t = threadIdx.x;
    int lane = t & 63;
    int wid = t >> 6;
    int wr = wid >> 1, wc = wid & 1;
    int row0 = blockIdx.x * 64;
    f32x4 acc[2][4] = {};

    int lr = lane >> 3;
    int lg = (lane & 7) ^ lr;

    for (int ks = 0; ks < KS; ++ks) {
        int k0 = ks * 64;
#pragma unroll
        for (int it = 0; it < 2; ++it) {
            int ci2 = wid * 2 + it;
            int r = ci2 * 8 + lr;
            int gr = min(row0 + r, M - 1);
            gll16(&A[(size_t)gr * HIDD + k0 + lg * 8], &As[ci2 * 512]);
        }
#pragma unroll
        for (int it = 0; it < 4; ++it) {
            int ci = wid * 4 + it;
            gll16(&WTp[(size_t)((ci * KS + ks) * 64 + lane) * 8], &Bs[ci * 512]);
        }
        __syncthreads();
#pragma unroll
        for (int h = 0; h < 2; ++h) {
            int q = h * 4 + (lane >> 4);
            bf16x8 a[2];
#pragma unroll
            for (int m = 0; m < 2; ++m) {
                int r = wr * 32 + m * 16 + (lane & 15);
                a[m] = *(const bf16x8*)&As[r * 64 + (q ^ (r & 7)) * 8];
            }
#pragma unroll
            for (int n = 0; n < 4; ++n) {
                int c = wc * 64 + n * 16 + (lane & 15);
                bf16x8 b = *(const bf16x8*)&Bs[c * 64 + (q ^ (c & 7)) * 8];
#pragma unroll
                for (int m = 0; m < 2; ++m)
                    acc[m][n] = __builtin_amdgcn_mfma_f32_16x16x32_bf16(a[m], b, acc[m][n], 0, 0, 0);
            }
        }
        __syncthreads();
    }
#pragma unroll
    for (int m = 0; m < 2; ++m) {
#pragma unroll
        for (int reg = 0; reg < 4; ++reg) {
            int row = row0 + wr * 32 + m * 16 + (lane >> 4) * 4 + reg;
            if (row < M) {
                float d = dinv[row];
#pragma unroll
                for (int n = 0; n < 4; ++n) {
                    int colg = wc * 64 + n * 16 + (lane & 15);
                    out[(size_t)row * 128 + colg] = f2bf(acc[m][n][reg] * d);
                }
            }
        }
    }
}

// ---------------- CSR aggregation (bf16 in/out, fp32 accum), tiered 16/8/4/1 gather ----------------

__device__ __forceinline__ void acc_edge(float& ax, float& ay, unsigned w) {
    ax += bf2f((ushort)(w & 0xffff));
    ay += bf2f((ushort)(w >> 16));
}

template <int U>
__device__ __forceinline__ int gather_tier(const ushort* __restrict__ hs,
                                           const int* __restrict__ col,
                                           int e, int e1, int l, float& ax, float& ay) {
    for (; e + U <= e1; e += U) {
        unsigned w[U];
#pragma unroll
        for (int u = 0; u < U; ++u)
            w[u] = *(const unsigned*)&hs[(size_t)col[e + u] * 128 + 2 * l];
#pragma unroll
        for (int u = 0; u < U; ++u) acc_edge(ax, ay, w[u]);
    }
    return e;
}

// agg1: h1 = bf16(relu(dinv*sum + b1))
__global__ void agg1_kernel(const ushort* __restrict__ hs, const int* __restrict__ row_ptr,
                            const int* __restrict__ col, const float* __restrict__ dinv,
                            const float* __restrict__ bias, ushort* __restrict__ out) {
    int wv = threadIdx.x >> 6;
    int l = threadIdx.x & 63;
    int i = blockIdx.x * 4 + wv;
    unsigned v0 = *(const unsigned*)&hs[(size_t)i * 128 + 2 * l];
    float ax = bf2f((ushort)(v0 & 0xffff));
    float ay = bf2f((ushort)(v0 >> 16));
    int e0 = row_ptr[i], e1 = row_ptr[i + 1];
    int e = e0;
    e = gather_tier<16>(hs, col, e, e1, l, ax, ay);
    e = gather_tier<8>(hs, col, e, e1, l, ax, ay);
    e = gather_tier<4>(hs, col, e, e1, l, ax, ay);
    for (; e < e1; ++e)
        acc_edge(ax, ay, *(const unsigned*)&hs[(size_t)col[e] * 128 + 2 * l]);
    float d = dinv[i];
    float ox = fmaxf(fmaf(ax, d, bias[2 * l]), 0.f);
    float oy = fmaxf(fmaf(ay, d, bias[2 * l + 1]), 0.f);
    unsigned o = (unsigned)f2bf(ox) | ((unsigned)f2bf(oy) << 16);
    *(unsigned*)&out[(size_t)i * 128 + 2 * l] = o;
}

// ---------------- fused agg2 + heads (heads hide under gather latency) ----------------

__global__ void agg2_heads_kernel(const ushort* __restrict__ hs, const int* __restrict__ row_ptr,
                                  const int* __restrict__ col, const float* __restrict__ dinv,
                                  const float* __restrict__ bias,
                                  const float* __restrict__ Wi, const float* __restrict__ bi,
                                  const float* __restrict__ Wl, const float* __restrict__ bl,
                                  float* __restrict__ out) {
    int wv = threadIdx.x >> 6;
    int l = threadIdx.x & 63;
    int i = blockIdx.x * 4 + wv;
    unsigned v0 = *(const unsigned*)&hs[(size_t)i * 128 + 2 * l];
    float ax = bf2f((ushort)(v0 & 0xffff));
    float ay = bf2f((ushort)(v0 >> 16));
    int e0 = row_ptr[i], e1 = row_ptr[i + 1];
    int e = e0;
    e = gather_tier<16>(hs, col, e, e1, l, ax, ay);
    e = gather_tier<8>(hs, col, e, e1, l, ax, ay);
    e = gather_tier<4>(hs, col, e, e1, l, ax, ay);
    for (; e < e1; ++e)
        acc_edge(ax, ay, *(const unsigned*)&hs[(size_t)col[e] * 128 + 2 * l]);
    float d = dinv[i];
    float ox = fmaxf(fmaf(ax, d, bias[2 * l]), 0.f);
    float oy = fmaxf(fmaf(ay, d, bias[2 * l + 1]), 0.f);

    // logits: lane l holds h2[2l], h2[2l+1]; Wi/Wl are [128][6] row-major
    float4 u0 = *(const float4*)&Wi[l * 12];
    float4 u1 = *(const float4*)&Wi[l * 12 + 4];
    float4 u2 = *(const float4*)&Wi[l * 12 + 8];
    float pi[6];
    pi[0] = ox * u0.x + oy * u1.z;
    pi[1] = ox * u0.y + oy * u1.w;
    pi[2] = ox * u0.z + oy * u2.x;
    pi[3] = ox * u0.w + oy * u2.y;
    pi[4] = ox * u1.x + oy * u2.z;
    pi[5] = ox * u1.y + oy * u2.w;
    u0 = *(const float4*)&Wl[l * 12];
    u1 = *(const float4*)&Wl[l * 12 + 4];
    u2 = *(const float4*)&Wl[l * 12 + 8];
    float pl[6];
    pl[0] = ox * u0.x + oy * u1.z;
    pl[1] = ox * u0.y + oy * u1.w;
    pl[2] = ox * u0.z + oy * u2.x;
    pl[3] = ox * u0.w + oy * u2.y;
    pl[4] = ox * u1.x + oy * u2.z;
    pl[5] = ox * u1.y + oy * u2.w;
#pragma unroll
    for (int off = 1; off < 64; off <<= 1) {
#pragma unroll
        for (int c = 0; c < 6; ++c) {
            pi[c] += __shfl_xor(pi[c], off);
            pl[c] += __shfl_xor(pl[c], off);
        }
    }
#pragma unroll
    for (int c = 0; c < 6; ++c) {
        pi[c] += bi[c];
        pl[c] += bl[c];
    }
    float mi = fmaxf(fmaxf(fmaxf(pi[0], pi[1]), fmaxf(pi[2], pi[3])), fmaxf(pi[4], pi[5]));
    float ml = fmaxf(fmaxf(fmaxf(pl[0], pl[1]), fmaxf(pl[2], pl[3])), fmaxf(pl[4], pl[5]));
    float si = 0.f, sl = 0.f;
#pragma unroll
    for (int c = 0; c < 6; ++c) {
        si += expf(pi[c] - mi);
        sl += expf(pl[c] - ml);
    }
    float lsi = mi + logf(si), lsl = ml + logf(sl);
#pragma unroll
    for (int c = 0; c < 6; ++c) {
        if (l == c)     out[(size_t)i * NC + c] = pi[c] - lsi;
        if (l == 6 + c) out[(size_t)NN * NC + (size_t)i * NC + c] = pl[c] - lsl;
    }
}

extern "C" void kernel_launch(void* const* d_in, const int* in_sizes, int n_in,
                              void* d_out, int out_size, void* d_ws, size_t ws_size,
                              hipStream_t stream) {
    const float* x  = (const float*)d_in[0];
    const int*   ei = (const int*)d_in[1];
    const float* W1 = (const float*)d_in[2];
    const float* b1 = (const float*)d_in[3];
    const float* W2 = (const float*)d_in[4];
    const float* b2 = (const float*)d_in[5];
    const float* Wi = (const float*)d_in[6];
    const float* bi = (const float*)d_in[7];
    const float* Wl = (const float*)d_in[8];
    const float* bl = (const float*)d_in[9];
    float* out = (float*)d_out;

    uint8_t* p = (uint8_t*)d_ws;
    auto alloc = [&](size_t bytes) {
        void* r = (void*)p;
        p += (bytes + 255) / 256 * 256;
        return r;
    };
    int* row_ptr = (int*)alloc((NN + 1) * sizeof(int));
    int* cursor  = (int*)alloc((NN + 64) * sizeof(int));   // +64: done counter lives at cursor[NN]
    int* col     = (int*)alloc(NE * sizeof(int));
    int* bsum    = (int*)alloc(64 * sizeof(int));
    float* dinv  = (float*)alloc(NN * sizeof(float));
    ushort* WT1p = (ushort*)alloc((size_t)KD * HIDD * sizeof(ushort));
    ushort* WT2p = (ushort*)alloc((size_t)HIDD * HIDD * sizeof(ushort));
    ushort* bufA = (ushort*)alloc((size_t)NN * HIDD * sizeof(ushort));
    ushort* bufB = (ushort*)alloc((size_t)NN * HIDD * sizeof(ushort));
    int* done = cursor + NN;

    const int CB = NE / 256;   // 3125
    const int PB = 56;         // pack blocks

    // zero cnt/cursor + done counter
    hipMemsetAsync(cursor, 0, (NN + 64) * sizeof(int), stream);
    count_prep_kernel<<<CB + PB, 256, 0, stream>>>(ei, cursor, W1, W2, WT1p, WT2p);
    scan_fused_kernel<<<196, 256, 0, stream>>>(cursor, row_ptr, dinv, bsum, cursor, done);
    fill_gemm1_kernel<<<CB + (NN + 63) / 64, 256, 0, stream>>>(ei, cursor, col,
                                                               x, WT1p, dinv, bufA, NN);
    agg1_kernel<<<NN / 4, 256, 0, stream>>>(bufA, row_ptr, col, dinv, b1, bufB);
    mfma_gemm2<<<(NN + 63) / 64, 256, 0, stream>>>(bufB, WT2p, dinv, bufA, NN);
    agg2_heads_kernel<<<NN / 4, 256, 0, stream>>>(bufA, row_ptr, col, dinv, b2,
                                                  Wi, bi, Wl, bl, out);
}

// Round 9
// 192.400 us; speedup vs baseline: 1.8616x; 1.3367x over previous
//
#include <hip/hip_runtime.h>
#include <hip/hip_bf16.h>

#define NN 50000
#define NE 800000
#define KD 768
#define HIDD 128
#define NC 6
#define PADW 64
#define OVCAP 262144

typedef __attribute__((ext_vector_type(8))) short bf16x8;
typedef __attribute__((ext_vector_type(4))) float f32x4;

__device__ __forceinline__ ushort f2bf(float f) {
    union { float f; unsigned u; } v; v.f = f;
    unsigned u = v.u + 0x7FFF + ((v.u >> 16) & 1);   // round-to-nearest-even
    return (ushort)(u >> 16);
}
__device__ __forceinline__ float bf2f(ushort h) {
    union { unsigned u; float f; } v; v.u = ((unsigned)h) << 16;
    return v.f;
}
__device__ __forceinline__ void gll16(const void* g, void* l) {
    __builtin_amdgcn_global_load_lds((const __attribute__((address_space(1))) void*)g,
                                     (__attribute__((address_space(3))) void*)l, 16, 0, 0);
}

// ---------------- weight prep granule (packed, gll-ready, swizzle baked in) ----------------

template <int KTOT>
__device__ __forceinline__ void pack_granule(const float* __restrict__ W,
                                             ushort* __restrict__ WTp, int gi) {
    const int KS = KTOT / 64;
    int ci = gi / (KS * 64);
    int rem = gi % (KS * 64);
    int ks = rem >> 6;
    int lane = rem & 63;
    int lr = lane >> 3;
    int lg = (lane & 7) ^ lr;
    int c = ci * 8 + lr;
    ushort tmp[8];
#pragma unroll
    for (int j = 0; j < 8; ++j)
        tmp[j] = f2bf(W[(size_t)(ks * 64 + lg * 8 + j) * HIDD + c]);
    *(bf16x8*)&WTp[(size_t)gi * 8] = *(bf16x8*)tmp;
}

// ---------------- K_A: weight pack (blocks 0..55) + single-pass padded-CSR fill ----------------

__global__ void pack_fill_kernel(const int* __restrict__ ei, int* __restrict__ cnt,
                                 int* __restrict__ pad_col, int* __restrict__ ov_cnt,
                                 int2* __restrict__ ov,
                                 const float* __restrict__ W1, const float* __restrict__ W2,
                                 ushort* __restrict__ WT1p, ushort* __restrict__ WT2p) {
    const int PB = 56;
    const int G1 = 16 * (KD / 64) * 64;     // 12288
    const int G2 = 16 * (HIDD / 64) * 64;   // 2048
    int b = blockIdx.x;
    if (b < PB) {
        int gi = b * 256 + threadIdx.x;
        if (gi < G1) pack_granule<KD>(W1, WT1p, gi);
        else if (gi < G1 + G2) pack_granule<HIDD>(W2, WT2p, gi - G1);
        return;
    }
    int e = (b - PB) * 256 + threadIdx.x;
    int sidx = ei[e];
    int d = ei[NE + e];
    sidx = min(max(sidx, 0), NN - 1);
    d = min(max(d, 0), NN - 1);
    int pos = atomicAdd(&cnt[d], 1);
    if (pos < PADW) {
        pad_col[(size_t)d * PADW + pos] = sidx;
    } else {
        int op = atomicAdd(ov_cnt, 1);
        if (op < OVCAP) ov[op] = make_int2(d, sidx);
    }
}

// ---------------- K_B: MFMA GEMM1 (no dinv) + dinv compute (trailing blocks) ----------------
// gemm blocks [0,782): hs1 = bf16(x@W1), BM=64,BN=128,BK=64, 4 waves (2x2).
// blocks [782, 782+196): dinv[i] = rsqrt(cnt[i]+1).

__global__ __launch_bounds__(256) void gemm1_dinv_kernel(
    const float* __restrict__ A, const ushort* __restrict__ WTp,
    const int* __restrict__ cnt, float* __restrict__ dinv,
    ushort* __restrict__ out, int M) {
    const int GB = (NN + 63) / 64;   // 782
    __shared__ ushort As[64 * 64];
    __shared__ ushort Bs[128 * 64];
    if (blockIdx.x >= GB) {
        int i = (blockIdx.x - GB) * 256 + threadIdx.x;
        if (i < NN) dinv[i] = rsqrtf((float)(cnt[i] + 1));
        return;
    }
    const int KS = KD / 64;
    int t = threadIdx.x;
    int lane = t & 63;
    int wid = t >> 6;
    int wr = wid >> 1, wc = wid & 1;
    int row0 = blockIdx.x * 64;
    f32x4 acc[2][4] = {};

    for (int ks = 0; ks < KS; ++ks) {
        int k0 = ks * 64;
#pragma unroll
        for (int it = 0; it < 4; ++it) {
            int r = (t >> 4) + it * 16;
            int k4 = t & 15;
            int gr = min(row0 + r, M - 1);
            float4 v = *(const float4*)&A[(size_t)gr * KD + k0 + k4 * 4];
            ushort4 w;
            w.x = f2bf(v.x); w.y = f2bf(v.y); w.z = f2bf(v.z); w.w = f2bf(v.w);
            int g = k4 >> 1, half = k4 & 1;
            *(ushort4*)&As[r * 64 + ((g ^ (r & 7)) * 8) + half * 4] = w;
        }
#pragma unroll
        for (int it = 0; it < 4; ++it) {
            int ci = wid * 4 + it;
            gll16(&WTp[(size_t)((ci * KS + ks) * 64 + lane) * 8], &Bs[ci * 512]);
        }
        __syncthreads();
#pragma unroll
        for (int h = 0; h < 2; ++h) {
            int q = h * 4 + (lane >> 4);
            bf16x8 a[2];
#pragma unroll
            for (int m = 0; m < 2; ++m) {
                int r = wr * 32 + m * 16 + (lane & 15);
                a[m] = *(const bf16x8*)&As[r * 64 + (q ^ (r & 7)) * 8];
            }
#pragma unroll
            for (int n = 0; n < 4; ++n) {
                int c = wc * 64 + n * 16 + (lane & 15);
                bf16x8 b = *(const bf16x8*)&Bs[c * 64 + (q ^ (c & 7)) * 8];
#pragma unroll
                for (int m = 0; m < 2; ++m)
                    acc[m][n] = __builtin_amdgcn_mfma_f32_16x16x32_bf16(a[m], b, acc[m][n], 0, 0, 0);
            }
        }
        __syncthreads();
    }
#pragma unroll
    for (int m = 0; m < 2; ++m) {
#pragma unroll
        for (int reg = 0; reg < 4; ++reg) {
            int row = row0 + wr * 32 + m * 16 + (lane >> 4) * 4 + reg;
            if (row < M) {
#pragma unroll
                for (int n = 0; n < 4; ++n) {
                    int colg = wc * 64 + n * 16 + (lane & 15);
                    out[(size_t)row * 128 + colg] = f2bf(acc[m][n][reg]);
                }
            }
        }
    }
}

// ---------------- MFMA GEMM2: hs2 = bf16(dinv*(h1@W2)), bf16 A via gll ----------------

__global__ __launch_bounds__(256) void mfma_gemm2(const ushort* __restrict__ A,
                                                  const ushort* __restrict__ WTp,
                                                  const float* __restrict__ dinv,
                                                  ushort* __restrict__ out, int M) {
    const int KS = HIDD / 64;   // 2
    __shared__ ushort As[64 * 64];
    __shared__ ushort Bs[128 * 64];
    int t = threadIdx.x;
    int lane = t & 63;
    int wid = t >> 6;
    int wr = wid >> 1, wc = wid & 1;
    int row0 = blockIdx.x * 64;
    f32x4 acc[2][4] = {};

    int lr = lane >> 3;
    int lg = (lane & 7) ^ lr;

    for (int ks = 0; ks < KS; ++ks) {
        int k0 = ks * 64;
#pragma unroll
        for (int it = 0; it < 2; ++it) {
            int ci2 = wid * 2 + it;
            int r = ci2 * 8 + lr;
            int gr = min(row0 + r, M - 1);
            gll16(&A[(size_t)gr * HIDD + k0 + lg * 8], &As[ci2 * 512]);
        }
#pragma unroll
        for (int it = 0; it < 4; ++it) {
            int ci = wid * 4 + it;
            gll16(&WTp[(size_t)((ci * KS + ks) * 64 + lane) * 8], &Bs[ci * 512]);
        }
        __syncthreads();
#pragma unroll
        for (int h = 0; h < 2; ++h) {
            int q = h * 4 + (lane >> 4);
            bf16x8 a[2];
#pragma unroll
            for (int m = 0; m < 2; ++m) {
                int r = wr * 32 + m * 16 + (lane & 15);
                a[m] = *(const bf16x8*)&As[r * 64 + (q ^ (r & 7)) * 8];
            }
#pragma unroll
            for (int n = 0; n < 4; ++n) {
                int c = wc * 64 + n * 16 + (lane & 15);
                bf16x8 b = *(const bf16x8*)&Bs[c * 64 + (q ^ (c & 7)) * 8];
#pragma unroll
                for (int m = 0; m < 2; ++m)
                    acc[m][n] = __builtin_amdgcn_mfma_f32_16x16x32_bf16(a[m], b, acc[m][n], 0, 0, 0);
            }
        }
        __syncthreads();
    }
#pragma unroll
    for (int m = 0; m < 2; ++m) {
#pragma unroll
        for (int reg = 0; reg < 4; ++reg) {
            int row = row0 + wr * 32 + m * 16 + (lane >> 4) * 4 + reg;
            if (row < M) {
                float d = dinv[row];
#pragma unroll
                for (int n = 0; n < 4; ++n) {
                    int colg = wc * 64 + n * 16 + (lane & 15);
                    out[(size_t)row * 128 + colg] = f2bf(acc[m][n][reg] * d);
                }
            }
        }
    }
}

// ---------------- padded-CSR aggregation helpers ----------------

__device__ __forceinline__ void acc_edge(float& ax, float& ay, unsigned w) {
    ax += bf2f((ushort)(w & 0xffff));
    ay += bf2f((ushort)(w >> 16));
}

// tier with per-edge dinv_j (agg1)
template <int U>
__device__ __forceinline__ int gather_tier_d(const ushort* __restrict__ hs,
                                             const int* __restrict__ cols,
                                             const float* __restrict__ dinv,
                                             int e, int e1, int l, float& ax, float& ay) {
    for (; e + U <= e1; e += U) {
        int j[U];
#pragma unroll
        for (int u = 0; u < U; ++u) j[u] = cols[e + u];
        unsigned w[U];
        float dj[U];
#pragma unroll
        for (int u = 0; u < U; ++u) {
            w[u] = *(const unsigned*)&hs[(size_t)j[u] * 128 + 2 * l];
            dj[u] = dinv[j[u]];
        }
#pragma unroll
        for (int u = 0; u < U; ++u) {
            ax = fmaf(dj[u], bf2f((ushort)(w[u] & 0xffff)), ax);
            ay = fmaf(dj[u], bf2f((ushort)(w[u] >> 16)), ay);
        }
    }
    return e;
}

// tier without dinv (agg2: input pre-scaled)
template <int U>
__device__ __forceinline__ int gather_tier(const ushort* __restrict__ hs,
                                           const int* __restrict__ cols,
                                           int e, int e1, int l, float& ax, float& ay) {
    for (; e + U <= e1; e += U) {
        unsigned w[U];
#pragma unroll
        for (int u = 0; u < U; ++u)
            w[u] = *(const unsigned*)&hs[(size_t)cols[e + u] * 128 + 2 * l];
#pragma unroll
        for (int u = 0; u < U; ++u) acc_edge(ax, ay, w[u]);
    }
    return e;
}

// ---------------- agg1: h1 = bf16(relu(dinv_i*(dinv_i*h_i + sum dinv_j*h_j) + b1)) ----------------

__global__ void agg1_kernel(const ushort* __restrict__ hs, const int* __restrict__ cnt,
                            const int* __restrict__ pad_col, const float* __restrict__ dinv,
                            const float* __restrict__ bias,
                            const int* __restrict__ ov_cnt, const int2* __restrict__ ov,
                            ushort* __restrict__ out) {
    int wv = threadIdx.x >> 6;
    int l = threadIdx.x & 63;
    int i = blockIdx.x * 4 + wv;
    float d = dinv[i];
    unsigned v0 = *(const unsigned*)&hs[(size_t)i * 128 + 2 * l];
    float ax = d * bf2f((ushort)(v0 & 0xffff));
    float ay = d * bf2f((ushort)(v0 >> 16));
    int deg = cnt[i];
    int n = min(deg, PADW);
    const int* cols = pad_col + (size_t)i * PADW;
    int e = 0;
    e = gather_tier_d<16>(hs, cols, dinv, e, n, l, ax, ay);
    e = gather_tier_d<8>(hs, cols, dinv, e, n, l, ax, ay);
    e = gather_tier_d<4>(hs, cols, dinv, e, n, l, ax, ay);
    for (; e < n; ++e) {
        int j = cols[e];
        unsigned w = *(const unsigned*)&hs[(size_t)j * 128 + 2 * l];
        float dj = dinv[j];
        ax = fmaf(dj, bf2f((ushort)(w & 0xffff)), ax);
        ay = fmaf(dj, bf2f((ushort)(w >> 16)), ay);
    }
    if (deg > PADW) {   // overflow rescue (never triggers for this input)
        int oc = min(*ov_cnt, OVCAP);
        for (int k = 0; k < oc; ++k) {
            int2 pr = ov[k];
            if (pr.x == i) {
                unsigned w = *(const unsigned*)&hs[(size_t)pr.y * 128 + 2 * l];
                float dj = dinv[pr.y];
                ax = fmaf(dj, bf2f((ushort)(w & 0xffff)), ax);
                ay = fmaf(dj, bf2f((ushort)(w >> 16)), ay);
            }
        }
    }
    float ox = fmaxf(fmaf(ax, d, bias[2 * l]), 0.f);
    float oy = fmaxf(fmaf(ay, d, bias[2 * l + 1]), 0.f);
    unsigned o = (unsigned)f2bf(ox) | ((unsigned)f2bf(oy) << 16);
    *(unsigned*)&out[(size_t)i * 128 + 2 * l] = o;
}

// ---------------- agg2 + heads (hs2 pre-scaled by dinv; heads hide under gather) ----------------

__global__ void agg2_heads_kernel(const ushort* __restrict__ hs, const int* __restrict__ cnt,
                                  const int* __restrict__ pad_col, const float* __restrict__ dinv,
                                  const float* __restrict__ bias,
                                  const int* __restrict__ ov_cnt, const int2* __restrict__ ov,
                                  const float* __restrict__ Wi, const float* __restrict__ bi,
                                  const float* __restrict__ Wl, const float* __restrict__ bl,
                                  float* __restrict__ out) {
    int wv = threadIdx.x >> 6;
    int l = threadIdx.x & 63;
    int i = blockIdx.x * 4 + wv;
    unsigned v0 = *(const unsigned*)&hs[(size_t)i * 128 + 2 * l];
    float ax = bf2f((ushort)(v0 & 0xffff));
    float ay = bf2f((ushort)(v0 >> 16));
    int deg = cnt[i];
    int n = min(deg, PADW);
    const int* cols = pad_col + (size_t)i * PADW;
    int e = 0;
    e = gather_tier<16>(hs, cols, e, n, l, ax, ay);
    e = gather_tier<8>(hs, cols, e, n, l, ax, ay);
    e = gather_tier<4>(hs, cols, e, n, l, ax, ay);
    for (; e < n; ++e)
        acc_edge(ax, ay, *(const unsigned*)&hs[(size_t)cols[e] * 128 + 2 * l]);
    if (deg > PADW) {
        int oc = min(*ov_cnt, OVCAP);
        for (int k = 0; k < oc; ++k) {
            int2 pr = ov[k];
            if (pr.x == i)
                acc_edge(ax, ay, *(const unsigned*)&hs[(size_t)pr.y * 128 + 2 * l]);
        }
    }
    float d = dinv[i];
    float ox = fmaxf(fmaf(ax, d, bias[2 * l]), 0.f);
    float oy = fmaxf(fmaf(ay, d, bias[2 * l + 1]), 0.f);

    // logits: lane l holds h2[2l], h2[2l+1]; Wi/Wl are [128][6] row-major
    float4 u0 = *(const float4*)&Wi[l * 12];
    float4 u1 = *(const float4*)&Wi[l * 12 + 4];
    float4 u2 = *(const float4*)&Wi[l * 12 + 8];
    float pi[6];
    pi[0] = ox * u0.x + oy * u1.z;
    pi[1] = ox * u0.y + oy * u1.w;
    pi[2] = ox * u0.z + oy * u2.x;
    pi[3] = ox * u0.w + oy * u2.y;
    pi[4] = ox * u1.x + oy * u2.z;
    pi[5] = ox * u1.y + oy * u2.w;
    u0 = *(const float4*)&Wl[l * 12];
    u1 = *(const float4*)&Wl[l * 12 + 4];
    u2 = *(const float4*)&Wl[l * 12 + 8];
    float pl[6];
    pl[0] = ox * u0.x + oy * u1.z;
    pl[1] = ox * u0.y + oy * u1.w;
    pl[2] = ox * u0.z + oy * u2.x;
    pl[3] = ox * u0.w + oy * u2.y;
    pl[4] = ox * u1.x + oy * u2.z;
    pl[5] = ox * u1.y + oy * u2.w;
#pragma unroll
    for (int off = 1; off < 64; off <<= 1) {
#pragma unroll
        for (int c = 0; c < 6; ++c) {
            pi[c] += __shfl_xor(pi[c], off);
            pl[c] += __shfl_xor(pl[c], off);
        }
    }
#pragma unroll
    for (int c = 0; c < 6; ++c) {
        pi[c] += bi[c];
        pl[c] += bl[c];
    }
    float mi = fmaxf(fmaxf(fmaxf(pi[0], pi[1]), fmaxf(pi[2], pi[3])), fmaxf(pi[4], pi[5]));
    float ml = fmaxf(fmaxf(fmaxf(pl[0], pl[1]), fmaxf(pl[2], pl[3])), fmaxf(pl[4], pl[5]));
    float si = 0.f, sl = 0.f;
#pragma unroll
    for (int c = 0; c < 6; ++c) {
        si += expf(pi[c] - mi);
        sl += expf(pl[c] - ml);
    }
    float lsi = mi + logf(si), lsl = ml + logf(sl);
#pragma unroll
    for (int c = 0; c < 6; ++c) {
        if (l == c)     out[(size_t)i * NC + c] = pi[c] - lsi;
        if (l == 6 + c) out[(size_t)NN * NC + (size_t)i * NC + c] = pl[c] - lsl;
    }
}

extern "C" void kernel_launch(void* const* d_in, const int* in_sizes, int n_in,
                              void* d_out, int out_size, void* d_ws, size_t ws_size,
                              hipStream_t stream) {
    const float* x  = (const float*)d_in[0];
    const int*   ei = (const int*)d_in[1];
    const float* W1 = (const float*)d_in[2];
    const float* b1 = (const float*)d_in[3];
    const float* W2 = (const float*)d_in[4];
    const float* b2 = (const float*)d_in[5];
    const float* Wi = (const float*)d_in[6];
    const float* bi = (const float*)d_in[7];
    const float* Wl = (const float*)d_in[8];
    const float* bl = (const float*)d_in[9];
    float* out = (float*)d_out;

    uint8_t* p = (uint8_t*)d_ws;
    auto alloc = [&](size_t bytes) {
        void* r = (void*)p;
        p += (bytes + 255) / 256 * 256;
        return r;
    };
    int* cnt      = (int*)alloc((NN + 64) * sizeof(int));   // cnt + ov_cnt at [NN]
    int* pad_col  = (int*)alloc((size_t)NN * PADW * sizeof(int));
    int2* ov      = (int2*)alloc((size_t)OVCAP * sizeof(int2));
    float* dinv   = (float*)alloc(NN * sizeof(float));
    ushort* WT1p  = (ushort*)alloc((size_t)KD * HIDD * sizeof(ushort));
    ushort* WT2p  = (ushort*)alloc((size_t)HIDD * HIDD * sizeof(ushort));
    ushort* bufA  = (ushort*)alloc((size_t)NN * HIDD * sizeof(ushort));
    ushort* bufB  = (ushort*)alloc((size_t)NN * HIDD * sizeof(ushort));
    int* ov_cnt = cnt + NN;

    const int FB = NE / 256;          // 3125 fill blocks
    const int PB = 56;                // pack blocks
    const int GB = (NN + 63) / 64;    // 782 gemm blocks
    const int DB = (NN + 255) / 256;  // 196 dinv blocks

    hipMemsetAsync(cnt, 0, (NN + 64) * sizeof(int), stream);
    // K_A: pack (first) + single-pass padded fill
    pack_fill_kernel<<<PB + FB, 256, 0, stream>>>(ei, cnt, pad_col, ov_cnt, ov,
                                                  W1, W2, WT1p, WT2p);
    // K_B: gemm1 (long blocks first) + dinv (trailing trivial blocks)
    gemm1_dinv_kernel<<<GB + DB, 256, 0, stream>>>(x, WT1p, cnt, dinv, bufA, NN);
    // agg1 -> h1
    agg1_kernel<<<NN / 4, 256, 0, stream>>>(bufA, cnt, pad_col, dinv, b1, ov_cnt, ov, bufB);
    // gemm2 -> hs2 (dinv-scaled)
    mfma_gemm2<<<GB, 256, 0, stream>>>(bufB, WT2p, dinv, bufA, NN);
    // agg2 + heads
    agg2_heads_kernel<<<NN / 4, 256, 0, stream>>>(bufA, cnt, pad_col, dinv, b2, ov_cnt, ov,
                                                  Wi, bi, Wl, bl, out);
}

// Round 10
// 174.612 us; speedup vs baseline: 2.0513x; 1.1019x over previous
//
#include <hip/hip_runtime.h>
#include <hip/hip_bf16.h>

#define NN 50000
#define NE 800000
#define KD 768
#define HIDD 128
#define NC 6
#define PADW 64
#define OVCAP 262144

typedef __attribute__((ext_vector_type(8))) short bf16x8;
typedef __attribute__((ext_vector_type(4))) float f32x4;

__device__ __forceinline__ ushort f2bf(float f) {
    union { float f; unsigned u; } v; v.f = f;
    unsigned u = v.u + 0x7FFF + ((v.u >> 16) & 1);   // round-to-nearest-even
    return (ushort)(u >> 16);
}
__device__ __forceinline__ float bf2f(ushort h) {
    union { unsigned u; float f; } v; v.u = ((unsigned)h) << 16;
    return v.f;
}
__device__ __forceinline__ void gll16(const void* g, void* l) {
    __builtin_amdgcn_global_load_lds((const __attribute__((address_space(1))) void*)g,
                                     (__attribute__((address_space(3))) void*)l, 16, 0, 0);
}
__device__ __forceinline__ float dinv_of(int c) {
    return rsqrtf((float)(c + 1));
}

// ---------------- weight prep granule (packed, gll-ready, swizzle baked in) ----------------

template <int KTOT>
__device__ __forceinline__ void pack_granule(const float* __restrict__ W,
                                             ushort* __restrict__ WTp, int gi) {
    const int KS = KTOT / 64;
    int ci = gi / (KS * 64);
    int rem = gi % (KS * 64);
    int ks = rem >> 6;
    int lane = rem & 63;
    int lr = lane >> 3;
    int lg = (lane & 7) ^ lr;
    int c = ci * 8 + lr;
    ushort tmp[8];
#pragma unroll
    for (int j = 0; j < 8; ++j)
        tmp[j] = f2bf(W[(size_t)(ks * 64 + lg * 8 + j) * HIDD + c]);
    *(bf16x8*)&WTp[(size_t)gi * 8] = *(bf16x8*)tmp;
}

// ---------------- K0: weight pack (blocks 0..55) + zero cnt/ov_cnt (trailing blocks) ----------------

__global__ void pack_zero_kernel(int* __restrict__ cnt,
                                 const float* __restrict__ W1, const float* __restrict__ W2,
                                 ushort* __restrict__ WT1p, ushort* __restrict__ WT2p) {
    const int PB = 56;
    const int G1 = 16 * (KD / 64) * 64;     // 12288
    const int G2 = 16 * (HIDD / 64) * 64;   // 2048
    int b = blockIdx.x;
    if (b < PB) {
        int gi = b * 256 + threadIdx.x;
        if (gi < G1) pack_granule<KD>(W1, WT1p, gi);
        else if (gi < G1 + G2) pack_granule<HIDD>(W2, WT2p, gi - G1);
    } else {
        int i = (b - PB) * 256 + threadIdx.x;
        if (i < NN + 64) cnt[i] = 0;
    }
}

// ---------------- K1: MFMA GEMM1 (blocks 0..781, FIRST) + padded-CSR fill (trailing) ----------------
// gemm: hs1 = bf16(x@W1), BM=64,BN=128,BK=64, 4 waves (2x2). No dinv (applied in agg1).
// fill: single atomic pass -> cnt (degrees) + pad_col rows (+ overflow list).

__global__ __launch_bounds__(256) void gemm1_fill_kernel(
    const float* __restrict__ A, const ushort* __restrict__ WTp,
    ushort* __restrict__ out, int M,
    const int* __restrict__ ei, int* __restrict__ cnt,
    int* __restrict__ pad_col, int* __restrict__ ov_cnt, int2* __restrict__ ov) {
    const int GB = (NN + 63) / 64;   // 782
    __shared__ ushort As[64 * 64];
    __shared__ ushort Bs[128 * 64];
    if (blockIdx.x >= GB) {
        int e = (blockIdx.x - GB) * 256 + threadIdx.x;
        int sidx = ei[e];
        int d = ei[NE + e];
        sidx = min(max(sidx, 0), NN - 1);
        d = min(max(d, 0), NN - 1);
        int pos = atomicAdd(&cnt[d], 1);
        if (pos < PADW) {
            pad_col[(size_t)d * PADW + pos] = sidx;
        } else {
            int op = atomicAdd(ov_cnt, 1);
            if (op < OVCAP) ov[op] = make_int2(d, sidx);
        }
        return;
    }
    const int KS = KD / 64;
    int t = threadIdx.x;
    int lane = t & 63;
    int wid = t >> 6;
    int wr = wid >> 1, wc = wid & 1;
    int row0 = blockIdx.x * 64;
    f32x4 acc[2][4] = {};

    for (int ks = 0; ks < KS; ++ks) {
        int k0 = ks * 64;
#pragma unroll
        for (int it = 0; it < 4; ++it) {
            int r = (t >> 4) + it * 16;
            int k4 = t & 15;
            int gr = min(row0 + r, M - 1);
            float4 v = *(const float4*)&A[(size_t)gr * KD + k0 + k4 * 4];
            ushort4 w;
            w.x = f2bf(v.x); w.y = f2bf(v.y); w.z = f2bf(v.z); w.w = f2bf(v.w);
            int g = k4 >> 1, half = k4 & 1;
            *(ushort4*)&As[r * 64 + ((g ^ (r & 7)) * 8) + half * 4] = w;
        }
#pragma unroll
        for (int it = 0; it < 4; ++it) {
            int ci = wid * 4 + it;
            gll16(&WTp[(size_t)((ci * KS + ks) * 64 + lane) * 8], &Bs[ci * 512]);
        }
        __syncthreads();
#pragma unroll
        for (int h = 0; h < 2; ++h) {
            int q = h * 4 + (lane >> 4);
            bf16x8 a[2];
#pragma unroll
            for (int m = 0; m < 2; ++m) {
                int r = wr * 32 + m * 16 + (lane & 15);
                a[m] = *(const bf16x8*)&As[r * 64 + (q ^ (r & 7)) * 8];
            }
#pragma unroll
            for (int n = 0; n < 4; ++n) {
                int c = wc * 64 + n * 16 + (lane & 15);
                bf16x8 b = *(const bf16x8*)&Bs[c * 64 + (q ^ (c & 7)) * 8];
#pragma unroll
                for (int m = 0; m < 2; ++m)
                    acc[m][n] = __builtin_amdgcn_mfma_f32_16x16x32_bf16(a[m], b, acc[m][n], 0, 0, 0);
            }
        }
        __syncthreads();
    }
#pragma unroll
    for (int m = 0; m < 2; ++m) {
#pragma unroll
        for (int reg = 0; reg < 4; ++reg) {
            int row = row0 + wr * 32 + m * 16 + (lane >> 4) * 4 + reg;
            if (row < M) {
#pragma unroll
                for (int n = 0; n < 4; ++n) {
                    int colg = wc * 64 + n * 16 + (lane & 15);
                    out[(size_t)row * 128 + colg] = f2bf(acc[m][n][reg]);
                }
            }
        }
    }
}

// ---------------- MFMA GEMM2: hs2 = bf16(dinv*(h1@W2)), bf16 A via gll; dinv from cnt ----------------

__global__ __launch_bounds__(256) void mfma_gemm2(const ushort* __restrict__ A,
                                                  const ushort* __restrict__ WTp,
                                                  const int* __restrict__ cnt,
                                                  ushort* __restrict__ out, int M) {
    const int KS = HIDD / 64;   // 2
    __shared__ ushort As[64 * 64];
    __shared__ ushort Bs[128 * 64];
    int t = threadIdx.x;
    int lane = t & 63;
    int wid = t >> 6;
    int wr = wid >> 1, wc = wid & 1;
    int row0 = blockIdx.x * 64;
    f32x4 acc[2][4] = {};

    int lr = lane >> 3;
    int lg = (lane & 7) ^ lr;

    for (int ks = 0; ks < KS; ++ks) {
        int k0 = ks * 64;
#pragma unroll
        for (int it = 0; it < 2; ++it) {
            int ci2 = wid * 2 + it;
            int r = ci2 * 8 + lr;
            int gr = min(row0 + r, M - 1);
            gll16(&A[(size_t)gr * HIDD + k0 + lg * 8], &As[ci2 * 512]);
        }
#pragma unroll
        for (int it = 0; it < 4; ++it) {
            int ci = wid * 4 + it;
            gll16(&WTp[(size_t)((ci * KS + ks) * 64 + lane) * 8], &Bs[ci * 512]);
        }
        __syncthreads();
#pragma unroll
        for (int h = 0; h < 2; ++h) {
            int q = h * 4 + (lane >> 4);
            bf16x8 a[2];
#pragma unroll
            for (int m = 0; m < 2; ++m) {
                int r = wr * 32 + m * 16 + (lane & 15);
                a[m] = *(const bf16x8*)&As[r * 64 + (q ^ (r & 7)) * 8];
            }
#pragma unroll
            for (int n = 0; n < 4; ++n) {
                int c = wc * 64 + n * 16 + (lane & 15);
                bf16x8 b = *(const bf16x8*)&Bs[c * 64 + (q ^ (c & 7)) * 8];
#pragma unroll
                for (int m = 0; m < 2; ++m)
                    acc[m][n] = __builtin_amdgcn_mfma_f32_16x16x32_bf16(a[m], b, acc[m][n], 0, 0, 0);
            }
        }
        __syncthreads();
    }
#pragma unroll
    for (int m = 0; m < 2; ++m) {
#pragma unroll
        for (int reg = 0; reg < 4; ++reg) {
            int row = row0 + wr * 32 + m * 16 + (lane >> 4) * 4 + reg;
            if (row < M) {
                float d = dinv_of(cnt[row]);
#pragma unroll
                for (int n = 0; n < 4; ++n) {
                    int colg = wc * 64 + n * 16 + (lane & 15);
                    out[(size_t)row * 128 + colg] = f2bf(acc[m][n][reg] * d);
                }
            }
        }
    }
}

// ---------------- padded-CSR aggregation helpers ----------------

__device__ __forceinline__ void acc_edge(float& ax, float& ay, unsigned w) {
    ax += bf2f((ushort)(w & 0xffff));
    ay += bf2f((ushort)(w >> 16));
}

// tier with per-edge dinv_j computed from cnt (agg1)
template <int U>
__device__ __forceinline__ int gather_tier_d(const ushort* __restrict__ hs,
                                             const int* __restrict__ cols,
                                             const int* __restrict__ cnt,
                                             int e, int e1, int l, float& ax, float& ay) {
    for (; e + U <= e1; e += U) {
        int j[U];
#pragma unroll
        for (int u = 0; u < U; ++u) j[u] = cols[e + u];
        unsigned w[U];
        float dj[U];
#pragma unroll
        for (int u = 0; u < U; ++u) {
            w[u] = *(const unsigned*)&hs[(size_t)j[u] * 128 + 2 * l];
            dj[u] = dinv_of(cnt[j[u]]);
        }
#pragma unroll
        for (int u = 0; u < U; ++u) {
            ax = fmaf(dj[u], bf2f((ushort)(w[u] & 0xffff)), ax);
            ay = fmaf(dj[u], bf2f((ushort)(w[u] >> 16)), ay);
        }
    }
    return e;
}

// tier without dinv (agg2: input pre-scaled)
template <int U>
__device__ __forceinline__ int gather_tier(const ushort* __restrict__ hs,
                                           const int* __restrict__ cols,
                                           int e, int e1, int l, float& ax, float& ay) {
    for (; e + U <= e1; e += U) {
        unsigned w[U];
#pragma unroll
        for (int u = 0; u < U; ++u)
            w[u] = *(const unsigned*)&hs[(size_t)cols[e + u] * 128 + 2 * l];
#pragma unroll
        for (int u = 0; u < U; ++u) acc_edge(ax, ay, w[u]);
    }
    return e;
}

// ---------------- agg1: h1 = bf16(relu(dinv_i*(dinv_i*h_i + sum dinv_j*h_j) + b1)) ----------------

__global__ void agg1_kernel(const ushort* __restrict__ hs, const int* __restrict__ cnt,
                            const int* __restrict__ pad_col,
                            const float* __restrict__ bias,
                            const int* __restrict__ ov_cnt, const int2* __restrict__ ov,
                            ushort* __restrict__ out) {
    int wv = threadIdx.x >> 6;
    int l = threadIdx.x & 63;
    int i = blockIdx.x * 4 + wv;
    int deg = cnt[i];
    float d = dinv_of(deg);
    unsigned v0 = *(const unsigned*)&hs[(size_t)i * 128 + 2 * l];
    float ax = d * bf2f((ushort)(v0 & 0xffff));
    float ay = d * bf2f((ushort)(v0 >> 16));
    int n = min(deg, PADW);
    const int* cols = pad_col + (size_t)i * PADW;
    int e = 0;
    e = gather_tier_d<16>(hs, cols, cnt, e, n, l, ax, ay);
    e = gather_tier_d<8>(hs, cols, cnt, e, n, l, ax, ay);
    e = gather_tier_d<4>(hs, cols, cnt, e, n, l, ax, ay);
    for (; e < n; ++e) {
        int j = cols[e];
        unsigned w = *(const unsigned*)&hs[(size_t)j * 128 + 2 * l];
        float dj = dinv_of(cnt[j]);
        ax = fmaf(dj, bf2f((ushort)(w & 0xffff)), ax);
        ay = fmaf(dj, bf2f((ushort)(w >> 16)), ay);
    }
    if (deg > PADW) {   // overflow rescue (never triggers for this input)
        int oc = min(*ov_cnt, OVCAP);
        for (int k = 0; k < oc; ++k) {
            int2 pr = ov[k];
            if (pr.x == i) {
                unsigned w = *(const unsigned*)&hs[(size_t)pr.y * 128 + 2 * l];
                float dj = dinv_of(cnt[pr.y]);
                ax = fmaf(dj, bf2f((ushort)(w & 0xffff)), ax);
                ay = fmaf(dj, bf2f((ushort)(w >> 16)), ay);
            }
        }
    }
    float ox = fmaxf(fmaf(ax, d, bias[2 * l]), 0.f);
    float oy = fmaxf(fmaf(ay, d, bias[2 * l + 1]), 0.f);
    unsigned o = (unsigned)f2bf(ox) | ((unsigned)f2bf(oy) << 16);
    *(unsigned*)&out[(size_t)i * 128 + 2 * l] = o;
}

// ---------------- agg2 + heads (hs2 pre-scaled by dinv; heads hide under gather) ----------------

__global__ void agg2_heads_kernel(const ushort* __restrict__ hs, const int* __restrict__ cnt,
                                  const int* __restrict__ pad_col,
                                  const float* __restrict__ bias,
                                  const int* __restrict__ ov_cnt, const int2* __restrict__ ov,
                                  const float* __restrict__ Wi, const float* __restrict__ bi,
                                  const float* __restrict__ Wl, const float* __restrict__ bl,
                                  float* __restrict__ out) {
    int wv = threadIdx.x >> 6;
    int l = threadIdx.x & 63;
    int i = blockIdx.x * 4 + wv;
    unsigned v0 = *(const unsigned*)&hs[(size_t)i * 128 + 2 * l];
    float ax = bf2f((ushort)(v0 & 0xffff));
    float ay = bf2f((ushort)(v0 >> 16));
    int deg = cnt[i];
    int n = min(deg, PADW);
    const int* cols = pad_col + (size_t)i * PADW;
    int e = 0;
    e = gather_tier<16>(hs, cols, e, n, l, ax, ay);
    e = gather_tier<8>(hs, cols, e, n, l, ax, ay);
    e = gather_tier<4>(hs, cols, e, n, l, ax, ay);
    for (; e < n; ++e)
        acc_edge(ax, ay, *(const unsigned*)&hs[(size_t)cols[e] * 128 + 2 * l]);
    if (deg > PADW) {
        int oc = min(*ov_cnt, OVCAP);
        for (int k = 0; k < oc; ++k) {
            int2 pr = ov[k];
            if (pr.x == i)
                acc_edge(ax, ay, *(const unsigned*)&hs[(size_t)pr.y * 128 + 2 * l]);
        }
    }
    float d = dinv_of(deg);
    float ox = fmaxf(fmaf(ax, d, bias[2 * l]), 0.f);
    float oy = fmaxf(fmaf(ay, d, bias[2 * l + 1]), 0.f);

    // logits: lane l holds h2[2l], h2[2l+1]; Wi/Wl are [128][6] row-major
    float4 u0 = *(const float4*)&Wi[l * 12];
    float4 u1 = *(const float4*)&Wi[l * 12 + 4];
    float4 u2 = *(const float4*)&Wi[l * 12 + 8];
    float pi[6];
    pi[0] = ox * u0.x + oy * u1.z;
    pi[1] = ox * u0.y + oy * u1.w;
    pi[2] = ox * u0.z + oy * u2.x;
    pi[3] = ox * u0.w + oy * u2.y;
    pi[4] = ox * u1.x + oy * u2.z;
    pi[5] = ox * u1.y + oy * u2.w;
    u0 = *(const float4*)&Wl[l * 12];
    u1 = *(const float4*)&Wl[l * 12 + 4];
    u2 = *(const float4*)&Wl[l * 12 + 8];
    float pl[6];
    pl[0] = ox * u0.x + oy * u1.z;
    pl[1] = ox * u0.y + oy * u1.w;
    pl[2] = ox * u0.z + oy * u2.x;
    pl[3] = ox * u0.w + oy * u2.y;
    pl[4] = ox * u1.x + oy * u2.z;
    pl[5] = ox * u1.y + oy * u2.w;
#pragma unroll
    for (int off = 1; off < 64; off <<= 1) {
#pragma unroll
        for (int c = 0; c < 6; ++c) {
            pi[c] += __shfl_xor(pi[c], off);
            pl[c] += __shfl_xor(pl[c], off);
        }
    }
#pragma unroll
    for (int c = 0; c < 6; ++c) {
        pi[c] += bi[c];
        pl[c] += bl[c];
    }
    float mi = fmaxf(fmaxf(fmaxf(pi[0], pi[1]), fmaxf(pi[2], pi[3])), fmaxf(pi[4], pi[5]));
    float ml = fmaxf(fmaxf(fmaxf(pl[0], pl[1]), fmaxf(pl[2], pl[3])), fmaxf(pl[4], pl[5]));
    float si = 0.f, sl = 0.f;
#pragma unroll
    for (int c = 0; c < 6; ++c) {
        si += expf(pi[c] - mi);
        sl += expf(pl[c] - ml);
    }
    float lsi = mi + logf(si), lsl = ml + logf(sl);
#pragma unroll
    for (int c = 0; c < 6; ++c) {
        if (l == c)     out[(size_t)i * NC + c] = pi[c] - lsi;
        if (l == 6 + c) out[(size_t)NN * NC + (size_t)i * NC + c] = pl[c] - lsl;
    }
}

extern "C" void kernel_launch(void* const* d_in, const int* in_sizes, int n_in,
                              void* d_out, int out_size, void* d_ws, size_t ws_size,
                              hipStream_t stream) {
    const float* x  = (const float*)d_in[0];
    const int*   ei = (const int*)d_in[1];
    const float* W1 = (const float*)d_in[2];
    const float* b1 = (const float*)d_in[3];
    const float* W2 = (const float*)d_in[4];
    const float* b2 = (const float*)d_in[5];
    const float* Wi = (const float*)d_in[6];
    const float* bi = (const float*)d_in[7];
    const float* Wl = (const float*)d_in[8];
    const float* bl = (const float*)d_in[9];
    float* out = (float*)d_out;

    uint8_t* p = (uint8_t*)d_ws;
    auto alloc = [&](size_t bytes) {
        void* r = (void*)p;
        p += (bytes + 255) / 256 * 256;
        return r;
    };
    int* cnt      = (int*)alloc((NN + 64) * sizeof(int));   // cnt + ov_cnt at [NN]
    int* pad_col  = (int*)alloc((size_t)NN * PADW * sizeof(int));
    int2* ov      = (int2*)alloc((size_t)OVCAP * sizeof(int2));
    ushort* WT1p  = (ushort*)alloc((size_t)KD * HIDD * sizeof(ushort));
    ushort* WT2p  = (ushort*)alloc((size_t)HIDD * HIDD * sizeof(ushort));
    ushort* bufA  = (ushort*)alloc((size_t)NN * HIDD * sizeof(ushort));
    ushort* bufB  = (ushort*)alloc((size_t)NN * HIDD * sizeof(ushort));
    int* ov_cnt = cnt + NN;

    const int FB = NE / 256;          // 3125 fill blocks
    const int PB = 56;                // pack blocks
    const int ZB = (NN + 64 + 255) / 256;  // 196 zero blocks
    const int GB = (NN + 63) / 64;    // 782 gemm blocks

    // K0: pack weights + zero cnt/ov_cnt
    pack_zero_kernel<<<PB + ZB, 256, 0, stream>>>(cnt, W1, W2, WT1p, WT2p);
    // K1: gemm1 (long blocks FIRST) overlapped with single-pass padded fill (trailing)
    gemm1_fill_kernel<<<GB + FB, 256, 0, stream>>>(x, WT1p, bufA, NN,
                                                   ei, cnt, pad_col, ov_cnt, ov);
    // agg1 -> h1 (dinv on the fly from cnt)
    agg1_kernel<<<NN / 4, 256, 0, stream>>>(bufA, cnt, pad_col, b1, ov_cnt, ov, bufB);
    // gemm2 -> hs2 (dinv-scaled)
    mfma_gemm2<<<GB, 256, 0, stream>>>(bufB, WT2p, cnt, bufA, NN);
    // agg2 + heads
    agg2_heads_kernel<<<NN / 4, 256, 0, stream>>>(bufA, cnt, pad_col, b2, ov_cnt, ov,
                                                  Wi, bi, Wl, bl, out);
}